// Round 3
// baseline (213.940 us; speedup 1.0000x reference)
//
#include <hip/hip_runtime.h>

// Involution (B=8, H=W=192, C=64, G=4, K=3, R=4) — fused, round 7.
// R6 post-mortem: fences worked (VGPR 108, scratch gone, 93->73us) but
// mask=0 pinned the kq ds_reads too: every region exposes ~120cy LDS
// latency + 18-read train before its FMAs. Prologue also fully exposed
// after __syncthreads.
// R7: (1) fence mask 0 -> 0x107 (ALU|VALU|SALU|DS_READ may cross; VMEM
// stays pinned so loads still can't sink = R5 failure mode blocked).
// kq ds_reads now hoist into the previous region's FMA shadow.
// (2) prologue loads issue BEFORE __syncthreads -> the barrier's
// mandatory vmcnt(0) drain absorbs their latency during sync.
// (3) launch_bounds(128,4): cap VGPR at 128 so hoisting can't drop us
// to the 2-waves/SIMD tier.
// GATE: if VGPR stays 108 and dur flat, scheduler ignored the mask ->
// next move is explicit source-level kq register prefetch.
// Memory floor (56+74 MB @ 6.3 TB/s) ~ 21 us.

#define B_   8
#define H_   192
#define W_   192
#define CR_  16
#define TH_  8
#define TW_  16
#define TILES_X (W_/TW_)                    // 12
#define TILES_PER_IMG (TILES_X*(H_/TH_))    // 288
#define NBLK (B_*TILES_PER_IMG)             // 2304
#define NPIX (TH_*TW_)                      // 128

constexpr float BN_EPS = 1e-3f;

__device__ __forceinline__ float4 mask4(float4 k, bool v) {
    k.x = v ? k.x : 0.f;
    k.y = v ? k.y : 0.f;
    k.z = v ? k.z : 0.f;
    k.w = v ? k.w : 0.f;
    return k;
}

__device__ __forceinline__ void fma4(float4& a, const float4 k, const float4 x) {
    a.x = fmaf(k.x, x.x, a.x);
    a.y = fmaf(k.y, x.y, a.y);
    a.z = fmaf(k.z, x.z, a.z);
    a.w = fmaf(k.w, x.w, a.w);
}

// Load row R (clamped) into ring slot S for both columns (6 float4 loads).
// Validity bit per slot in rv; columns share the row so one bit suffices.
#define LROWS(S, R)                                                         \
    do {                                                                    \
        int rr_ = (R);                                                      \
        if (!INTERIOR) {                                                    \
            if ((unsigned)rr_ < (unsigned)H_) rv |= (1 << (S));             \
            else                              rv &= ~(1 << (S));            \
            rr_ = rr_ < 0 ? 0 : (rr_ >= H_ ? H_ - 1 : rr_);                 \
        }                                                                   \
        const int rb_ = rr_ * (W_ * 16);                                    \
        rgA[S][0] = x4[rb_ + coA[0]];                                       \
        rgA[S][1] = x4[rb_ + coA[1]];                                       \
        rgA[S][2] = x4[rb_ + coA[2]];                                       \
        rgB[S][0] = x4[rb_ + coB[0]];                                       \
        rgB[S][1] = x4[rb_ + coB[1]];                                       \
        rgB[S][2] = x4[rb_ + coB[2]];                                       \
    } while (0)

// Compute pixel row th0+I for both columns from ring slots (I..I+2)&3.
#define COMP(I)                                                             \
    do {                                                                    \
        const float4* kqA_ = &s_kern[((I) * TW_ + wslot) * 9];              \
        const float4* kqB_ = &s_kern[((I) * TW_ + wslot + 8) * 9];          \
        float4 aA_ = make_float4(0.f, 0.f, 0.f, 0.f);                       \
        float4 aB_ = make_float4(0.f, 0.f, 0.f, 0.f);                       \
        _Pragma("unroll")                                                   \
        for (int ti_ = 0; ti_ < 3; ++ti_) {                                 \
            const int s_ = ((I) + ti_) & 3;                                 \
            _Pragma("unroll")                                               \
            for (int tj_ = 0; tj_ < 3; ++tj_) {                             \
                float4 kA_ = kqA_[ti_ * 3 + tj_];                           \
                float4 kB_ = kqB_[ti_ * 3 + tj_];                           \
                if (!INTERIOR) {                                            \
                    kA_ = mask4(kA_, (((rv >> s_) & (cmA >> tj_)) & 1));    \
                    kB_ = mask4(kB_, (((rv >> s_) & (cmB >> tj_)) & 1));    \
                }                                                           \
                fma4(aA_, kA_, rgA[s_][tj_]);                               \
                fma4(aB_, kB_, rgB[s_][tj_]);                               \
            }                                                               \
        }                                                                   \
        const int ob_ = (th0 + (I)) * (W_ * 16);                            \
        o4[ob_ + (wA << 4) + c4i] = aA_;                                    \
        o4[ob_ + (wB << 4) + c4i] = aB_;                                    \
    } while (0)

// ALU(0x1)|VALU(0x2)|SALU(0x4)|DS_READ(0x100) may cross; VMEM (0x10/20/40)
// pinned: global loads can never sink out of their region (the R5 squash),
// but kq ds_reads + address ALU hoist into the previous region's FMAs.
#define SFENCE __builtin_amdgcn_sched_barrier(0x107)

template <bool INTERIOR>
__device__ __forceinline__ void phase_b(const float4* __restrict__ x4,
                                        float4* __restrict__ o4,
                                        const float4* __restrict__ s_kern,
                                        int th0, int tw0, int tid)
{
    const int wslot = tid >> 4;   // 0..7 -> columns wslot and wslot+8
    const int c4i   = tid & 15;   // float4 channel chunk
    const int wA = tw0 + wslot;
    const int wB = tw0 + wslot + 8;

    // Column float4-offsets within a row (clamped; validity zeroes the
    // kern weight, matching zero-padding semantics).
    int coA[3], coB[3];
    int cmA = 7, cmB = 7;
    #pragma unroll
    for (int tj = 0; tj < 3; ++tj) {
        int wa = wA + tj - 1;
        int wb = wB + tj - 1;
        if (!INTERIOR) {
            if ((unsigned)wa >= (unsigned)W_) cmA &= ~(1 << tj);
            if ((unsigned)wb >= (unsigned)W_) cmB &= ~(1 << tj);
            wa = wa < 0 ? 0 : (wa >= W_ ? W_ - 1 : wa);
            wb = wb < 0 ? 0 : (wb >= W_ ? W_ - 1 : wb);
        }
        coA[tj] = (wa << 4) + c4i;
        coB[tj] = (wb << 4) + c4i;
    }

    float4 rgA[4][3], rgB[4][3];   // 96 VGPR ring, all indices static
    int rv = 0xF;

    // Prologue BEFORE the barrier: the compiler's vmcnt(0) drain at
    // s_barrier absorbs these 24 loads' latency while the block syncs
    // (they don't depend on s_kern; the barrier orders the ds side).
    LROWS(0, th0 - 1);
    LROWS(1, th0 + 0);
    LROWS(2, th0 + 1);
    LROWS(3, th0 + 2);

    __syncthreads();

    SFENCE;
    // Steady state: region i = { COMP(i), prefetch row th0+i+3 }.
    // Row th0+i+3 lands in the slot retired by COMP(i); first use is
    // COMP(i+2) — two full regions of FMA+LDS work after issue.
    COMP(0); LROWS(0, th0 + 3);
    SFENCE;
    COMP(1); LROWS(1, th0 + 4);
    SFENCE;
    COMP(2); LROWS(2, th0 + 5);
    SFENCE;
    COMP(3); LROWS(3, th0 + 6);
    SFENCE;
    COMP(4); LROWS(0, th0 + 7);
    SFENCE;
    COMP(5); LROWS(1, th0 + 8);
    SFENCE;
    COMP(6);
    SFENCE;
    COMP(7);
}

#undef LROWS
#undef COMP

__global__ __launch_bounds__(128, 4)
void invol_fused(const float* __restrict__ x,
                 const float* __restrict__ w1,
                 const float* __restrict__ b1,
                 const float* __restrict__ gamma,
                 const float* __restrict__ beta,
                 const float* __restrict__ mean,
                 const float* __restrict__ var,
                 const float* __restrict__ w2,
                 const float* __restrict__ b2,
                 float* __restrict__ out)
{
    // 128 pixels * 9 float4 (36 kern floats, tap-major, g minor) = 18 KB
    __shared__ float4 s_kern[NPIX * 9];

    const int bid = blockIdx.x;
    // XCD swizzle: 2304 = 8 * 288; each XCD owns one image for L2 locality.
    const int img = bid & 7;
    const int tin = bid >> 3;
    const int th0 = (tin / TILES_X) * TH_;
    const int tw0 = (tin % TILES_X) * TW_;

    const int tid = threadIdx.x;

    // ---------------- Phase A: kernel generation (1 thread = 1 pixel) -------
    {
        const int r = tid >> 4, cc = tid & 15;
        const int h = th0 + r, w = tw0 + cc;
        const float4* xp = reinterpret_cast<const float4*>(
            x + (((size_t)((img * H_ + h) * W_ + w)) << 6));

        float td[CR_];
        #pragma unroll
        for (int d = 0; d < CR_; ++d) td[d] = 0.f;

        // t = x @ w1   (weight addresses wave-uniform -> s_load, SMEM pipe)
        #pragma unroll
        for (int c4 = 0; c4 < 16; ++c4) {
            const float4 xv = xp[c4];
            const float xs[4] = {xv.x, xv.y, xv.z, xv.w};
            #pragma unroll
            for (int k = 0; k < 4; ++k) {
                const float* wr = w1 + (c4 * 4 + k) * CR_;
                #pragma unroll
                for (int d = 0; d < CR_; ++d)
                    td[d] = fmaf(xs[k], wr[d], td[d]);
            }
        }

        // + b1, BN (inference), ReLU — folded affine
        #pragma unroll
        for (int d = 0; d < CR_; ++d) {
            const float a = gamma[d] * rsqrtf(var[d] + BN_EPS);
            const float c = (b1[d] - mean[d]) * a + beta[d];
            td[d] = fmaxf(fmaf(td[d], a, c), 0.f);
        }

        // kern = t @ w2 + b2  (e = tap*4 + g)
        float ke[36];
        #pragma unroll
        for (int e = 0; e < 36; ++e) ke[e] = b2[e];
        #pragma unroll
        for (int d = 0; d < CR_; ++d) {
            const float t = td[d];
            const float* wr = w2 + d * 36;
            #pragma unroll
            for (int e = 0; e < 36; ++e)
                ke[e] = fmaf(t, wr[e], ke[e]);
        }

        // stride 36 words (144 B): conflict-free b128 (measured 0 conflicts)
        float4* skq = &s_kern[tid * 9];
        #pragma unroll
        for (int t9 = 0; t9 < 9; ++t9)
            skq[t9] = make_float4(ke[t9 * 4 + 0], ke[t9 * 4 + 1],
                                  ke[t9 * 4 + 2], ke[t9 * 4 + 3]);
    }

    // ---------------- Phase B: 9-tap multiply-reduce, column walk -----------
    // (barrier is inside phase_b, after the prologue loads issue; the
    // interior/boundary branch is block-uniform so the barrier is legal)
    const float4* x4 = reinterpret_cast<const float4*>(x) +
                       (size_t)img * (H_ * W_ * 16);
    float4* o4 = reinterpret_cast<float4*>(out) +
                 (size_t)img * (H_ * W_ * 16);

    const bool interior = (th0 > 0) && (th0 + TH_ < H_) &&
                          (tw0 > 0) && (tw0 + TW_ < W_);
    if (interior)
        phase_b<true >(x4, o4, s_kern, th0, tw0, tid);
    else
        phase_b<false>(x4, o4, s_kern, th0, tw0, tid);
}

extern "C" void kernel_launch(void* const* d_in, const int* in_sizes, int n_in,
                              void* d_out, int out_size, void* d_ws, size_t ws_size,
                              hipStream_t stream) {
    const float* x     = (const float*)d_in[0];
    const float* w1    = (const float*)d_in[1];
    const float* b1    = (const float*)d_in[2];
    const float* gamma = (const float*)d_in[3];
    const float* beta  = (const float*)d_in[4];
    const float* mean  = (const float*)d_in[5];
    const float* var   = (const float*)d_in[6];
    const float* w2    = (const float*)d_in[7];
    const float* b2    = (const float*)d_in[8];
    float* out = (float*)d_out;

    invol_fused<<<dim3(NBLK), dim3(128), 0, stream>>>(
        x, w1, b1, gamma, beta, mean, var, w2, b2, out);
}

// Round 4
// 172.748 us; speedup vs baseline: 1.2385x; 1.2385x over previous
//
#include <hip/hip_runtime.h>

// Involution (B=8, H=W=192, C=64, G=4, K=3, R=4) — fused, round 8.
// R7 post-mortem: __launch_bounds__(128,4) forced a 64-VGPR budget
// (hipcc's effective cap is one tier below the naive 512/waves model;
// cf. R3's (256,8)->32). The 96-VGPR ring spilled wholesale: WRITE_SIZE
// 73.7->121.7 MB (+48MB scratch = the ring round-tripping), dur 73->110us.
// TOOLCHAIN FACT: (128,2) => cap 256 (held 108 in R6); (128,4) => cap 64.
// R8: revert that ONE line to (128,2). Keep R7's two intended mechanisms,
// now cleanly attributable vs R6's 73us baseline:
//   (a) fence mask 0x107 (ALU|VALU|SALU|DS_READ cross; VMEM pinned) —
//       kq ds_reads hoist into the previous region's FMA shadow, loads
//       still cannot sink (R5 failure mode stays blocked; stores pin FMAs).
//   (b) 24-load prologue before __syncthreads — the barrier's mandatory
//       vmcnt(0) drain absorbs prologue latency while the block syncs.
// GATE: VGPR must read >100 & WRITE must read 73728. dur <68 => mask
// helps; ~73 => neutral (next lever is occupancy); >80 => mask hurts.
// Memory floor (56+74 MB @ 6.3 TB/s) ~ 21 us.

#define B_   8
#define H_   192
#define W_   192
#define CR_  16
#define TH_  8
#define TW_  16
#define TILES_X (W_/TW_)                    // 12
#define TILES_PER_IMG (TILES_X*(H_/TH_))    // 288
#define NBLK (B_*TILES_PER_IMG)             // 2304
#define NPIX (TH_*TW_)                      // 128

constexpr float BN_EPS = 1e-3f;

__device__ __forceinline__ float4 mask4(float4 k, bool v) {
    k.x = v ? k.x : 0.f;
    k.y = v ? k.y : 0.f;
    k.z = v ? k.z : 0.f;
    k.w = v ? k.w : 0.f;
    return k;
}

__device__ __forceinline__ void fma4(float4& a, const float4 k, const float4 x) {
    a.x = fmaf(k.x, x.x, a.x);
    a.y = fmaf(k.y, x.y, a.y);
    a.z = fmaf(k.z, x.z, a.z);
    a.w = fmaf(k.w, x.w, a.w);
}

// Load row R (clamped) into ring slot S for both columns (6 float4 loads).
// Validity bit per slot in rv; columns share the row so one bit suffices.
#define LROWS(S, R)                                                         \
    do {                                                                    \
        int rr_ = (R);                                                      \
        if (!INTERIOR) {                                                    \
            if ((unsigned)rr_ < (unsigned)H_) rv |= (1 << (S));             \
            else                              rv &= ~(1 << (S));            \
            rr_ = rr_ < 0 ? 0 : (rr_ >= H_ ? H_ - 1 : rr_);                 \
        }                                                                   \
        const int rb_ = rr_ * (W_ * 16);                                    \
        rgA[S][0] = x4[rb_ + coA[0]];                                       \
        rgA[S][1] = x4[rb_ + coA[1]];                                       \
        rgA[S][2] = x4[rb_ + coA[2]];                                       \
        rgB[S][0] = x4[rb_ + coB[0]];                                       \
        rgB[S][1] = x4[rb_ + coB[1]];                                       \
        rgB[S][2] = x4[rb_ + coB[2]];                                       \
    } while (0)

// Compute pixel row th0+I for both columns from ring slots (I..I+2)&3.
#define COMP(I)                                                             \
    do {                                                                    \
        const float4* kqA_ = &s_kern[((I) * TW_ + wslot) * 9];              \
        const float4* kqB_ = &s_kern[((I) * TW_ + wslot + 8) * 9];          \
        float4 aA_ = make_float4(0.f, 0.f, 0.f, 0.f);                       \
        float4 aB_ = make_float4(0.f, 0.f, 0.f, 0.f);                       \
        _Pragma("unroll")                                                   \
        for (int ti_ = 0; ti_ < 3; ++ti_) {                                 \
            const int s_ = ((I) + ti_) & 3;                                 \
            _Pragma("unroll")                                               \
            for (int tj_ = 0; tj_ < 3; ++tj_) {                             \
                float4 kA_ = kqA_[ti_ * 3 + tj_];                           \
                float4 kB_ = kqB_[ti_ * 3 + tj_];                           \
                if (!INTERIOR) {                                            \
                    kA_ = mask4(kA_, (((rv >> s_) & (cmA >> tj_)) & 1));    \
                    kB_ = mask4(kB_, (((rv >> s_) & (cmB >> tj_)) & 1));    \
                }                                                           \
                fma4(aA_, kA_, rgA[s_][tj_]);                               \
                fma4(aB_, kB_, rgB[s_][tj_]);                               \
            }                                                               \
        }                                                                   \
        const int ob_ = (th0 + (I)) * (W_ * 16);                            \
        o4[ob_ + (wA << 4) + c4i] = aA_;                                    \
        o4[ob_ + (wB << 4) + c4i] = aB_;                                    \
    } while (0)

// ALU(0x1)|VALU(0x2)|SALU(0x4)|DS_READ(0x100) may cross; VMEM (0x10/20/40)
// pinned: global loads can never sink out of their region (the R5 squash),
// but kq ds_reads + address ALU hoist into the previous region's FMAs.
// FMAs can't sink either: their stores are VMEM_WRITE-pinned per region.
#define SFENCE __builtin_amdgcn_sched_barrier(0x107)

template <bool INTERIOR>
__device__ __forceinline__ void phase_b(const float4* __restrict__ x4,
                                        float4* __restrict__ o4,
                                        const float4* __restrict__ s_kern,
                                        int th0, int tw0, int tid)
{
    const int wslot = tid >> 4;   // 0..7 -> columns wslot and wslot+8
    const int c4i   = tid & 15;   // float4 channel chunk
    const int wA = tw0 + wslot;
    const int wB = tw0 + wslot + 8;

    // Column float4-offsets within a row (clamped; validity zeroes the
    // kern weight, matching zero-padding semantics).
    int coA[3], coB[3];
    int cmA = 7, cmB = 7;
    #pragma unroll
    for (int tj = 0; tj < 3; ++tj) {
        int wa = wA + tj - 1;
        int wb = wB + tj - 1;
        if (!INTERIOR) {
            if ((unsigned)wa >= (unsigned)W_) cmA &= ~(1 << tj);
            if ((unsigned)wb >= (unsigned)W_) cmB &= ~(1 << tj);
            wa = wa < 0 ? 0 : (wa >= W_ ? W_ - 1 : wa);
            wb = wb < 0 ? 0 : (wb >= W_ ? W_ - 1 : wb);
        }
        coA[tj] = (wa << 4) + c4i;
        coB[tj] = (wb << 4) + c4i;
    }

    float4 rgA[4][3], rgB[4][3];   // 96 VGPR ring, all indices static
    int rv = 0xF;

    // Prologue BEFORE the barrier: the compiler's vmcnt(0) drain at
    // s_barrier absorbs these 24 loads' latency while the block syncs
    // (they don't depend on s_kern; the barrier orders the ds side).
    LROWS(0, th0 - 1);
    LROWS(1, th0 + 0);
    LROWS(2, th0 + 1);
    LROWS(3, th0 + 2);

    __syncthreads();

    SFENCE;
    // Steady state: region i = { COMP(i), prefetch row th0+i+3 }.
    // Row th0+i+3 lands in the slot retired by COMP(i); first use is
    // COMP(i+2) — two full regions of FMA+LDS work after issue.
    COMP(0); LROWS(0, th0 + 3);
    SFENCE;
    COMP(1); LROWS(1, th0 + 4);
    SFENCE;
    COMP(2); LROWS(2, th0 + 5);
    SFENCE;
    COMP(3); LROWS(3, th0 + 6);
    SFENCE;
    COMP(4); LROWS(0, th0 + 7);
    SFENCE;
    COMP(5); LROWS(1, th0 + 8);
    SFENCE;
    COMP(6);
    SFENCE;
    COMP(7);
}

#undef LROWS
#undef COMP

__global__ __launch_bounds__(128, 2)
void invol_fused(const float* __restrict__ x,
                 const float* __restrict__ w1,
                 const float* __restrict__ b1,
                 const float* __restrict__ gamma,
                 const float* __restrict__ beta,
                 const float* __restrict__ mean,
                 const float* __restrict__ var,
                 const float* __restrict__ w2,
                 const float* __restrict__ b2,
                 float* __restrict__ out)
{
    // 128 pixels * 9 float4 (36 kern floats, tap-major, g minor) = 18 KB
    __shared__ float4 s_kern[NPIX * 9];

    const int bid = blockIdx.x;
    // XCD swizzle: 2304 = 8 * 288; each XCD owns one image for L2 locality.
    const int img = bid & 7;
    const int tin = bid >> 3;
    const int th0 = (tin / TILES_X) * TH_;
    const int tw0 = (tin % TILES_X) * TW_;

    const int tid = threadIdx.x;

    // ---------------- Phase A: kernel generation (1 thread = 1 pixel) -------
    {
        const int r = tid >> 4, cc = tid & 15;
        const int h = th0 + r, w = tw0 + cc;
        const float4* xp = reinterpret_cast<const float4*>(
            x + (((size_t)((img * H_ + h) * W_ + w)) << 6));

        float td[CR_];
        #pragma unroll
        for (int d = 0; d < CR_; ++d) td[d] = 0.f;

        // t = x @ w1   (weight addresses wave-uniform -> s_load, SMEM pipe)
        #pragma unroll
        for (int c4 = 0; c4 < 16; ++c4) {
            const float4 xv = xp[c4];
            const float xs[4] = {xv.x, xv.y, xv.z, xv.w};
            #pragma unroll
            for (int k = 0; k < 4; ++k) {
                const float* wr = w1 + (c4 * 4 + k) * CR_;
                #pragma unroll
                for (int d = 0; d < CR_; ++d)
                    td[d] = fmaf(xs[k], wr[d], td[d]);
            }
        }

        // + b1, BN (inference), ReLU — folded affine
        #pragma unroll
        for (int d = 0; d < CR_; ++d) {
            const float a = gamma[d] * rsqrtf(var[d] + BN_EPS);
            const float c = (b1[d] - mean[d]) * a + beta[d];
            td[d] = fmaxf(fmaf(td[d], a, c), 0.f);
        }

        // kern = t @ w2 + b2  (e = tap*4 + g)
        float ke[36];
        #pragma unroll
        for (int e = 0; e < 36; ++e) ke[e] = b2[e];
        #pragma unroll
        for (int d = 0; d < CR_; ++d) {
            const float t = td[d];
            const float* wr = w2 + d * 36;
            #pragma unroll
            for (int e = 0; e < 36; ++e)
                ke[e] = fmaf(t, wr[e], ke[e]);
        }

        // stride 36 words (144 B): conflict-free b128 (measured 0 conflicts)
        float4* skq = &s_kern[tid * 9];
        #pragma unroll
        for (int t9 = 0; t9 < 9; ++t9)
            skq[t9] = make_float4(ke[t9 * 4 + 0], ke[t9 * 4 + 1],
                                  ke[t9 * 4 + 2], ke[t9 * 4 + 3]);
    }

    // ---------------- Phase B: 9-tap multiply-reduce, column walk -----------
    // (barrier is inside phase_b, after the prologue loads issue; the
    // interior/boundary branch is block-uniform so the barrier is legal)
    const float4* x4 = reinterpret_cast<const float4*>(x) +
                       (size_t)img * (H_ * W_ * 16);
    float4* o4 = reinterpret_cast<float4*>(out) +
                 (size_t)img * (H_ * W_ * 16);

    const bool interior = (th0 > 0) && (th0 + TH_ < H_) &&
                          (tw0 > 0) && (tw0 + TW_ < W_);
    if (interior)
        phase_b<true >(x4, o4, s_kern, th0, tw0, tid);
    else
        phase_b<false>(x4, o4, s_kern, th0, tw0, tid);
}

extern "C" void kernel_launch(void* const* d_in, const int* in_sizes, int n_in,
                              void* d_out, int out_size, void* d_ws, size_t ws_size,
                              hipStream_t stream) {
    const float* x     = (const float*)d_in[0];
    const float* w1    = (const float*)d_in[1];
    const float* b1    = (const float*)d_in[2];
    const float* gamma = (const float*)d_in[3];
    const float* beta  = (const float*)d_in[4];
    const float* mean  = (const float*)d_in[5];
    const float* var   = (const float*)d_in[6];
    const float* w2    = (const float*)d_in[7];
    const float* b2    = (const float*)d_in[8];
    float* out = (float*)d_out;

    invol_fused<<<dim3(NBLK), dim3(128), 0, stream>>>(
        x, w1, b1, gamma, beta, mean, var, w2, b2, out);
}